// Round 6
// baseline (963.154 us; speedup 1.0000x reference)
//
#include <hip/hip_runtime.h>

// Problem constants (fixed by the reference): T=512, B=64, I=256, H=512.
#define T_DIM 512
#define B_DIM 64
#define I_DIM 256
#define H_DIM 512
#define BH_DIM (B_DIM * H_DIM)   // 32768

// ---------------------------------------------------------------------------
// Round-12: xw_gemm (unchanged from R11) + TWO-STREAM scan.
//
// R11 post-mortem: scan = 740us = 3470cy/step, decomposed as exposed
// publish->detect RT (~1400-1700cy incl. poll quantization) + hh-fma (~500)
// + barrier/publish/skew. The ih hoist removed the work that used to hide
// the RT. Fix: each block runs TWO independent recurrences (batches 2k and
// 2k+1, same row-chunk rb -> SAME W_hh registers, SAME 4 partner blocks).
// While stream A's partners' publishes propagate (~RT), the block computes
// stream B's step, and vice versa. Each poll gets ~a half-iteration
// (~1400cy) of RT coverage -> speculative first load usually hits.
// 128 blocks x 512 threads, 1 block/CU, all co-resident (liveness).
//
// Waitcnt-drain audit (barriers drain vmcnt on this compiler):
//   - vB spec load: issued right AFTER barA, consumed before barB (poll B).
//   - xw prefetch (t+1): issued right AFTER barB, drained at next barA
//     (~1300cy later), consumed at next iteration's publishes.
//   - vA spec load: issued at loop bottom, consumed at next top (poll A)
//     BEFORE barA -- its wait is the poll itself.
// Protocol: proven R8/R11 agent-scope tagged words (tag = t+1), parity
// double-buffered; ABA-safe per stream by the standard chain argument.
// Deadlock-free: deps are forward-only in (t, stream) order.
// ---------------------------------------------------------------------------

// ---------------- Kernel 1: xw pre-pass GEMM (unchanged, R11) ----------------
__global__ __launch_bounds__(256) void xw_gemm(
    const float* __restrict__ x, const float* __restrict__ wih,
    const float* __restrict__ bih, const float* __restrict__ bhh,
    float* __restrict__ out) {
  __shared__ __align__(16) float As[32][128];  // [k][m]
  __shared__ __align__(16) float Bs[32][128];  // [k][n]

  const int bm = blockIdx.x >> 2;   // 0..255 (m-tile)
  const int bn = blockIdx.x & 3;    // 0..3   (n-tile)
  const int m0 = bm * 128, n0 = bn * 128;
  const int tid = threadIdx.x;      // 0..255
  const int tx = tid & 15, ty = tid >> 4;
  const int ml = tid & 127, kq = tid >> 7;  // staging map

  float acc[8][8];
#pragma unroll
  for (int r = 0; r < 8; r++)
#pragma unroll
    for (int c = 0; c < 8; c++) acc[r][c] = 0.f;

  for (int kc = 0; kc < I_DIM; kc += 32) {
    const float4* xr = (const float4*)(x + (size_t)(m0 + ml) * I_DIM + kc + kq * 16);
    const float4* br = (const float4*)(wih + (size_t)(n0 + ml) * I_DIM + kc + kq * 16);
    float4 av[4], bv[4];
#pragma unroll
    for (int j = 0; j < 4; j++) { av[j] = xr[j]; bv[j] = br[j]; }

    __syncthreads();
#pragma unroll
    for (int j = 0; j < 4; j++) {
      const int k = kq * 16 + j * 4;
      As[k + 0][ml] = av[j].x; As[k + 1][ml] = av[j].y;
      As[k + 2][ml] = av[j].z; As[k + 3][ml] = av[j].w;
      Bs[k + 0][ml] = bv[j].x; Bs[k + 1][ml] = bv[j].y;
      Bs[k + 2][ml] = bv[j].z; Bs[k + 3][ml] = bv[j].w;
    }
    __syncthreads();

#pragma unroll 4
    for (int kk = 0; kk < 32; kk++) {
      const float4 a0 = *(const float4*)&As[kk][ty * 4];
      const float4 a1 = *(const float4*)&As[kk][64 + ty * 4];
      const float4 b0 = *(const float4*)&Bs[kk][tx * 4];
      const float4 b1 = *(const float4*)&Bs[kk][64 + tx * 4];
      const float ar[8] = {a0.x, a0.y, a0.z, a0.w, a1.x, a1.y, a1.z, a1.w};
      const float br_[8] = {b0.x, b0.y, b0.z, b0.w, b1.x, b1.y, b1.z, b1.w};
#pragma unroll
      for (int r = 0; r < 8; r++)
#pragma unroll
        for (int c = 0; c < 8; c++) acc[r][c] = fmaf(ar[r], br_[c], acc[r][c]);
    }
  }

  const float4 bi0 = *(const float4*)(bih + n0 + tx * 4);
  const float4 bh0 = *(const float4*)(bhh + n0 + tx * 4);
  const float4 bi1 = *(const float4*)(bih + n0 + 64 + tx * 4);
  const float4 bh1 = *(const float4*)(bhh + n0 + 64 + tx * 4);
  const float4 bb0 = make_float4(bi0.x + bh0.x, bi0.y + bh0.y, bi0.z + bh0.z, bi0.w + bh0.w);
  const float4 bb1 = make_float4(bi1.x + bh1.x, bi1.y + bh1.y, bi1.z + bh1.z, bi1.w + bh1.w);

#pragma unroll
  for (int r = 0; r < 8; r++) {
    const int m = m0 + ((r < 4) ? (ty * 4 + r) : (64 + ty * 4 + (r - 4)));
    float4* orow = (float4*)(out + (size_t)m * H_DIM + n0);
    orow[tx] = make_float4(acc[r][0] + bb0.x, acc[r][1] + bb0.y,
                           acc[r][2] + bb0.z, acc[r][3] + bb0.w);
    orow[16 + tx] = make_float4(acc[r][4] + bb1.x, acc[r][5] + bb1.y,
                                acc[r][6] + bb1.z, acc[r][7] + bb1.w);
  }
}

// ---------------- Kernel 2: two-stream recurrent scan ----------------

// 16-lane sum on the VALU pipe (DPP): quad_perm 0xB1, 0x4E, row_ror:4, :8.
__device__ __forceinline__ float row16_sum(float v) {
  int m;
  m = __builtin_amdgcn_update_dpp(0, __float_as_int(v), 0xB1, 0xF, 0xF, true);
  v += __int_as_float(m);
  m = __builtin_amdgcn_update_dpp(0, __float_as_int(v), 0x4E, 0xF, 0xF, true);
  v += __int_as_float(m);
  m = __builtin_amdgcn_update_dpp(0, __float_as_int(v), 0x124, 0xF, 0xF, true);
  v += __int_as_float(m);
  m = __builtin_amdgcn_update_dpp(0, __float_as_int(v), 0x128, 0xF, 0xF, true);
  v += __int_as_float(m);
  return v;
}

// hh accumulation for one stream: 4 rows x 8 float4, then 16-lane reduce.
// Returns the reduced accumulator selected per cg (valid for cg<4).
__device__ __forceinline__ float hh_acc(const float* hb,
                                        const float4 (&w)[4][8], int cg) {
  float a0 = 0.f, a1 = 0.f, a2 = 0.f, a3 = 0.f;
#pragma unroll
  for (int i = 0; i < 8; i++) {
    const float4 hv = ((const float4*)hb)[i * 16 + cg];
    a0 = fmaf(w[0][i].x, hv.x, a0); a0 = fmaf(w[0][i].y, hv.y, a0);
    a0 = fmaf(w[0][i].z, hv.z, a0); a0 = fmaf(w[0][i].w, hv.w, a0);
    a1 = fmaf(w[1][i].x, hv.x, a1); a1 = fmaf(w[1][i].y, hv.y, a1);
    a1 = fmaf(w[1][i].z, hv.z, a1); a1 = fmaf(w[1][i].w, hv.w, a1);
    a2 = fmaf(w[2][i].x, hv.x, a2); a2 = fmaf(w[2][i].y, hv.y, a2);
    a2 = fmaf(w[2][i].z, hv.z, a2); a2 = fmaf(w[2][i].w, hv.w, a2);
    a3 = fmaf(w[3][i].x, hv.x, a3); a3 = fmaf(w[3][i].y, hv.y, a3);
    a3 = fmaf(w[3][i].z, hv.z, a3); a3 = fmaf(w[3][i].w, hv.w, a3);
  }
  a0 = row16_sum(a0);
  a1 = row16_sum(a1);
  a2 = row16_sum(a2);
  a3 = row16_sum(a3);
  return (cg == 0) ? a0 : (cg == 1) ? a1 : (cg == 2) ? a2 : a3;
}

__global__ __launch_bounds__(512, 2) void rnn_scan2(
    const float* __restrict__ whh, float* __restrict__ out,
    unsigned long long* __restrict__ stage) {
  __shared__ __align__(16) float hbA[2][H_DIM];  // 4 KB stream-A h dbuf
  __shared__ __align__(16) float hbB[2][H_DIM];  // 4 KB stream-B h dbuf

  const int k   = blockIdx.x & 31;       // batch pair 0..31
  const int rb  = blockIdx.x >> 5;       // row-chunk 0..3
  const int b0  = 2 * k, b1 = 2 * k + 1;
  const int tid = threadIdx.x;           // 0..511
  const int rg  = tid >> 4;              // 0..31
  const int cg  = tid & 15;              // 0..15
  const int j0  = rb * 128 + rg * 4;     // first of my 4 rows
  const int jj  = j0 + cg;               // publish index (cg<4 lanes)

  // spin target: one partner element each for threads 0..383 (skip own chunk)
  const int pj = (tid < rb * 128) ? tid : tid + 128;

  // ---- W_hh chunk -> registers (once; shared by both streams) ----
  float4 w[4][8];
#pragma unroll
  for (int r = 0; r < 4; r++) {
    const float4* wr = (const float4*)(whh + (size_t)(j0 + r) * H_DIM);
#pragma unroll
    for (int i = 0; i < 8; i++) w[r][i] = wr[i * 16 + cg];
  }

  float* __restrict__ outA = out + (size_t)b0 * H_DIM;  // t-stride = BH_DIM
  float* __restrict__ outB = out + (size_t)b1 * H_DIM;
  unsigned long long* __restrict__ stgA0 = stage + (size_t)b0 * H_DIM;
  unsigned long long* __restrict__ stgA1 = stage + (size_t)(64 + b0) * H_DIM;
  unsigned long long* __restrict__ stgB0 = stage + (size_t)b1 * H_DIM;
  unsigned long long* __restrict__ stgB1 = stage + (size_t)(64 + b1) * H_DIM;

  float hlastA = 0.f, hlastB = 0.f;

  // ---- t = 0: h_0 = relu(xw_0) for both streams; publish (tag 1) ----
  if (cg < 4) {
    const float hA = fmaxf(outA[jj], 0.f);
    const float hB = fmaxf(outB[jj], 0.f);
    union { float f; unsigned int u; } ca, cb; ca.f = hA; cb.f = hB;
    __hip_atomic_store(&stgA0[jj], (1ULL << 32) | (unsigned long long)ca.u,
                       __ATOMIC_RELAXED, __HIP_MEMORY_SCOPE_AGENT);
    __hip_atomic_store(&stgB0[jj], (1ULL << 32) | (unsigned long long)cb.u,
                       __ATOMIC_RELAXED, __HIP_MEMORY_SCOPE_AGENT);
    __builtin_nontemporal_store(hA, &outA[jj]);
    __builtin_nontemporal_store(hB, &outB[jj]);
    hbA[0][jj] = hA;
    hbB[0][jj] = hB;
    hlastA = hA;
    hlastB = hB;
  }

  // xw for t=1 (consumed at the first iteration's publishes)
  float xwA_cur = 0.f, xwB_cur = 0.f;
  if (cg < 4) {
    xwA_cur = __builtin_nontemporal_load(&outA[(size_t)BH_DIM + jj]);
    xwB_cur = __builtin_nontemporal_load(&outB[(size_t)BH_DIM + jj]);
  }

  // speculative first poll-load for stream A, t=1 (parity 0)
  unsigned long long vA = 0;
  if (tid < 384)
    vA = __hip_atomic_load(stgA0 + pj, __ATOMIC_RELAXED,
                           __HIP_MEMORY_SCOPE_AGENT);

  // ---- main scan ----
  for (int t = 1; t < T_DIM; t++) {
    const int p = (t - 1) & 1;            // parity of h_{t-1}
    const unsigned int want = (unsigned int)t;  // tag carried by h_{t-1}
    float* o_tA = outA + (size_t)t * BH_DIM;
    float* o_tB = outB + (size_t)t * BH_DIM;

    // A-poll: finish (speculative value from loop bottom usually hits)
    if (tid < 384) {
      unsigned long long* slot = (p ? stgA1 : stgA0) + pj;
      unsigned long long v = vA;
      while ((unsigned int)(v >> 32) != want)
        v = __hip_atomic_load(slot, __ATOMIC_RELAXED,
                              __HIP_MEMORY_SCOPE_AGENT);
      union { unsigned int u; float f; } cv; cv.u = (unsigned int)v;
      hbA[p][pj] = cv.f;
    }
    __syncthreads();  // barA: h_{t-1}^A complete in LDS

    // speculative first poll-load for stream B (hides under fma A)
    unsigned long long vB = 0;
    if (tid < 384)
      vB = __hip_atomic_load((p ? stgB1 : stgB0) + pj, __ATOMIC_RELAXED,
                             __HIP_MEMORY_SCOPE_AGENT);

    // fma A + reduce + publish
    const float accA = hh_acc(hbA[p], w, cg);
    if (cg < 4) {
      const float h = fmaxf(accA + xwA_cur, 0.f);
      union { float f; unsigned int u; } cv; cv.f = h;
      unsigned long long* sb = (t & 1) ? stgA1 : stgA0;
      __hip_atomic_store(&sb[jj],
                         ((unsigned long long)(unsigned int)(t + 1) << 32) |
                             (unsigned long long)cv.u,
                         __ATOMIC_RELAXED, __HIP_MEMORY_SCOPE_AGENT);
      __builtin_nontemporal_store(h, &o_tA[jj]);
      hbA[t & 1][jj] = h;
      hlastA = h;
    }

    // B-poll
    if (tid < 384) {
      unsigned long long* slot = (p ? stgB1 : stgB0) + pj;
      unsigned long long v = vB;
      while ((unsigned int)(v >> 32) != want)
        v = __hip_atomic_load(slot, __ATOMIC_RELAXED,
                              __HIP_MEMORY_SCOPE_AGENT);
      union { unsigned int u; float f; } cv; cv.u = (unsigned int)v;
      hbB[p][pj] = cv.f;
    }
    __syncthreads();  // barB: h_{t-1}^B complete in LDS

    // xw prefetch for t+1 (drains at next barA ~1300cy later; consumed at
    // next iteration's publishes)
    float xwA_n = 0.f, xwB_n = 0.f;
    if (cg < 4 && t + 1 < T_DIM) {
      xwA_n = __builtin_nontemporal_load(&outA[(size_t)(t + 1) * BH_DIM + jj]);
      xwB_n = __builtin_nontemporal_load(&outB[(size_t)(t + 1) * BH_DIM + jj]);
    }

    // fma B + reduce + publish
    const float accB = hh_acc(hbB[p], w, cg);
    if (cg < 4) {
      const float h = fmaxf(accB + xwB_cur, 0.f);
      union { float f; unsigned int u; } cv; cv.f = h;
      unsigned long long* sb = (t & 1) ? stgB1 : stgB0;
      __hip_atomic_store(&sb[jj],
                         ((unsigned long long)(unsigned int)(t + 1) << 32) |
                             (unsigned long long)cv.u,
                         __ATOMIC_RELAXED, __HIP_MEMORY_SCOPE_AGENT);
      __builtin_nontemporal_store(h, &o_tB[jj]);
      hbB[t & 1][jj] = h;
      hlastB = h;
    }

    // speculative first poll-load for stream A of t+1 (parity t&1);
    // consumed at next top-of-loop BEFORE barA -> no barrier drain stall
    if (tid < 384)
      vA = __hip_atomic_load(((t & 1) ? stgA1 : stgA0) + pj, __ATOMIC_RELAXED,
                             __HIP_MEMORY_SCOPE_AGENT);

    xwA_cur = xwA_n;
    xwB_cur = xwB_n;
  }

  // h_final = h_{T-1} for both streams
  if (cg < 4) {
    __builtin_nontemporal_store(
        hlastA, &out[(size_t)T_DIM * BH_DIM + (size_t)b0 * H_DIM + jj]);
    __builtin_nontemporal_store(
        hlastB, &out[(size_t)T_DIM * BH_DIM + (size_t)b1 * H_DIM + jj]);
  }
}

extern "C" void kernel_launch(void* const* d_in, const int* in_sizes, int n_in,
                              void* d_out, int out_size, void* d_ws, size_t ws_size,
                              hipStream_t stream) {
  const float* x   = (const float*)d_in[0];  // [T,B,I]
  const float* wih = (const float*)d_in[1];  // [H,I]
  const float* whh = (const float*)d_in[2];  // [H,H]
  const float* bih = (const float*)d_in[3];  // [H]
  const float* bhh = (const float*)d_in[4];  // [H]
  float* out = (float*)d_out;                // [T,B,H] output ++ [B,H] h_final
  // staging: 2 parities x 64 batches x 512 tagged 8B words = 512 KB
  unsigned long long* stage = (unsigned long long*)d_ws;

  // Pass 1: xw = x @ wih^T + bih + bhh  -> written into out[0 .. T*B*H)
  xw_gemm<<<1024, 256, 0, stream>>>(x, wih, bih, bhh, out);
  // Pass 2: two-stream recurrent scan (batch pair per block, shared W_hh)
  rnn_scan2<<<128, 512, 0, stream>>>(whh, out, stage);
}